// Round 4
// baseline (545.858 us; speedup 1.0000x reference)
//
#include <hip/hip_runtime.h>
#include <hip/hip_bf16.h>
#include <cstdint>
#include <cstddef>

// IR-Net binary conv 3x3 s1 p1 + BN(inference) + hardtanh, B=32 Cin=Cout=256 H=W=56.
// sign(x), sign(std(W)) ternary -> exact bf16 MFMA implicit GEMM.
// R4: 8-wave block (256co x 128px), wave-private W double-buffer in LDS fed by
//     global_load_lds (no W barriers), X span dbuf with 1 raw s_barrier per
//     cin-block, uniform counted s_waitcnt vmcnt(4), setprio around MFMA.

typedef short short8 __attribute__((ext_vector_type(8)));
typedef float floatx4 __attribute__((ext_vector_type(4)));

#define CIN   256
#define COUT  256
#define SPAT  3136   // 56*56
#define SPAD  3364   // 58*58 padded spatial
#define BATCH 32
#define SPAN  256    // padded-index rows staged per 128-px tile (halo included)

// ---------------- weight prep: standardize, sign, scatter to fragment order ----------------
__device__ inline float block_reduce(float v, float* red, int t) {
  red[t] = v; __syncthreads();
#pragma unroll
  for (int o = 128; o > 0; o >>= 1) {
    if (t < o) red[t] += red[t + o];
    __syncthreads();
  }
  float r = red[0];
  __syncthreads();
  return r;
}

__global__ __launch_bounds__(256) void prep_w_kernel(
    const float* __restrict__ wgt, const float* __restrict__ gamma,
    const float* __restrict__ beta, const float* __restrict__ rmean,
    const float* __restrict__ rvar, uint16_t* __restrict__ wfrag,
    float* __restrict__ Sc, float* __restrict__ Tc) {
  const int co = blockIdx.x;
  const int t  = threadIdx.x;
  __shared__ float red[256];
  const float* wc = wgt + (size_t)co * 2304;
  float v[9];
#pragma unroll
  for (int j = 0; j < 9; ++j) v[j] = wc[t + j * 256];
  float s = 0.f;
#pragma unroll
  for (int j = 0; j < 9; ++j) s += v[j];
  const float total = block_reduce(s, red, t);
  const float mean = total * (1.0f / 2304.0f);
  float ss = 0.f, sa = 0.f;
#pragma unroll
  for (int j = 0; j < 9; ++j) {
    float d = v[j] - mean;
    ss += d * d;
    sa += fabsf(d);
  }
  const float var_sum = block_reduce(ss, red, t);
  const float abs_sum = block_reduce(sa, red, t);
  const float stdv = sqrtf(var_sum / 2303.0f);       // unbiased (ddof=1)
  const float mean_abs = abs_sum / (2304.0f * stdv); // mean |bw|
  const float sw = exp2f(rintf(log2f(mean_abs)));    // half-even like jnp.round

  const int coblk = co >> 4, l15w = co & 15;
#pragma unroll
  for (int j = 0; j < 9; ++j) {
    int i = t + j * 256;          // i = cin*9 + tap  (OIHW flat)
    int cin = i / 9;
    int tap = i - cin * 9;
    float d = v[j] - mean;
    uint16_t bits = (d > 0.f) ? 0x3F80u : ((d < 0.f) ? 0xBF80u : 0u); // bf16 +-1 / 0
    // fragment order: [tap][c0i][coblk(16)][kk(2)][lane(64)][e(8)]
    int c0i = cin >> 6, cl = cin & 63;
    int kk = cl >> 5, chunk = (cl >> 3) & 3, e = cl & 7;
    int lanew = l15w | (chunk << 4);
    size_t flat = ((((size_t)(tap * 4 + c0i) * 16 + coblk) * 2 + kk) * 64 + lanew) * 8 + e;
    wfrag[flat] = bits;
  }
  if (t == 0) {
    float inv = gamma[co] / sqrtf(rvar[co] + 1e-5f);
    Sc[co] = sw * inv;
    Tc[co] = beta[co] - rmean[co] * inv;
  }
}

// ---------------- halo clear: zero only the 228 pad pixels per image ----------------
__global__ __launch_bounds__(256) void halo_kernel(uint16_t* __restrict__ xp) {
  const int b = blockIdx.x;
  uint16_t* xpb = xp + (size_t)b * SPAD * CIN;
  const short8 z = (short8){0, 0, 0, 0, 0, 0, 0, 0};
  for (int q = threadIdx.x; q < 228 * 32; q += 256) {
    int p = q >> 5, c = q & 31;
    int pp;
    if (p < 58)       pp = p;                      // top row 0
    else if (p < 116) pp = 57 * 58 + (p - 58);     // bottom row 57
    else if (p < 172) pp = (p - 116 + 1) * 58;     // left col, rows 1..56
    else              pp = (p - 172 + 1) * 58 + 57;// right col, rows 1..56
    *(short8*)(xpb + (size_t)pp * CIN + c * 8) = z;
  }
}

// ---------------- activation pack: sign(x) -> bf16, padded [b][58*58][cin] ----------------
__global__ __launch_bounds__(256) void pack_x_kernel(const float* __restrict__ x,
                                                     uint16_t* __restrict__ xp) {
  const int b   = blockIdx.y;
  const int s0  = blockIdx.x * 64;
  const int tid = threadIdx.x;
  __shared__ uint16_t xt[64][272];
  const int g  = tid >> 6;
  const int si = tid & 63;
  const float* xb = x + ((size_t)b * CIN + g * 64) * SPAT + s0 + si;
#pragma unroll 4
  for (int c2 = 0; c2 < 32; ++c2) {
    float v0 = xb[(size_t)(2 * c2) * SPAT];
    float v1 = xb[(size_t)(2 * c2 + 1) * SPAT];
    uint32_t b0 = (v0 > 0.f) ? 0x3F80u : ((v0 < 0.f) ? 0xBF80u : 0u);
    uint32_t b1 = (v1 > 0.f) ? 0x3F80u : ((v1 < 0.f) ? 0xBF80u : 0u);
    *(uint32_t*)&xt[si][g * 64 + 2 * c2] = b0 | (b1 << 16);
  }
  __syncthreads();
  const int row = tid >> 2;
  const int sub = tid & 3;
  const int s = s0 + row;
  const int h = s / 56, w = s - h * 56;
  uint16_t* dst = xp + ((size_t)b * SPAD + (size_t)(h + 1) * 58 + (w + 1)) * CIN + sub * 64;
#pragma unroll
  for (int j = 0; j < 8; ++j)
    *(short8*)(dst + j * 8) = *(const short8*)&xt[row][sub * 64 + j * 8];
}

// ---------------- async global->LDS, 16B ----------------
__device__ __forceinline__ void gload_lds16(const void* g, void* l) {
  __builtin_amdgcn_global_load_lds(
      (const __attribute__((address_space(1))) uint32_t*)g,
      (__attribute__((address_space(3))) uint32_t*)l, 16, 0, 0);
}

// ---------------- binary conv as implicit GEMM (bf16 MFMA) ----------------
// Block: 256co x 128px, one image; 8 waves, wave = 32co x 128px (2m x 8n frags).
// X: padded-span [SPAN][64cin] XOR-swizzled, dbuf, 1 raw barrier per c0i.
// W: wave-private LDS dbuf [2][4KB], filled by global_load_lds 2 taps ahead.
__global__ __launch_bounds__(512, 1) void conv_kernel(
    const uint16_t* __restrict__ xp, const uint16_t* __restrict__ wfrag,
    const float* __restrict__ Sc, const float* __restrict__ Tc,
    float* __restrict__ out) {
  const int tile = blockIdx.x;           // 0..24
  const int b    = blockIdx.y;           // 0..31
  const int s0   = tile * 128;

  const int tid  = threadIdx.x;
  const int lane = tid & 63;
  const int wave = tid >> 6;             // 0..7, wave's 32-co stripe
  const int l15  = lane & 15;
  const int chp  = lane >> 4;            // k-chunk position 0..3

  __shared__ uint16_t Xs[2][SPAN * 64];  // 64 KB
  __shared__ uint16_t Wb[8][2][2048];    // 64 KB, wave-private dbuf

  const int h0   = s0 / 56;
  const int base = s0 + 2 * h0;          // = padded(s0) - 59, padded(s)=s+2h+59

  int offn[8];
#pragma unroll
  for (int n = 0; n < 8; ++n) {
    int s = s0 + n * 16 + l15;
    int sc = s < SPAT ? s : SPAT - 1;    // dummy px clamped (stores masked)
    int h = sc / 56;
    offn[n] = sc + 2 * h + 59 - base;
  }

  const uint16_t* xb = xp + (size_t)b * SPAD * CIN;
  auto issueX = [&](int bufi, int c0e) {
#pragma unroll
    for (int j = 0; j < 4; ++j) {
      int q = wave * 256 + j * 64 + lane;   // 2048 x 16B chunks block-wide
      int row = q >> 3, c = q & 7;
      int gr = base + row;
      if (gr > SPAD - 1) gr = SPAD - 1;     // clamp: only feeds dummy px
      gload_lds16(xb + (size_t)gr * CIN + c0e + ((c ^ (row & 7)) << 3),
                  &Xs[bufi][(size_t)q << 3]);
    }
  };
  auto issueW = [&](int g) {               // g = global step (c0i*9+tap), wrapped
    int c0 = g / 9, tp = g - c0 * 9;
    const uint16_t* src = wfrag + ((size_t)((tp * 4 + c0) * 16 + wave * 2)) * 1024
                        + (size_t)lane * 8;
    uint16_t* dst = &Wb[wave][g & 1][lane * 8];
#pragma unroll
    for (int i = 0; i < 4; ++i)
      gload_lds16(src + i * 512, dst + i * 512);
  };

  floatx4 acc[2][8];
#pragma unroll
  for (int m = 0; m < 2; ++m)
#pragma unroll
    for (int n = 0; n < 8; ++n) acc[m][n] = (floatx4){0.f, 0.f, 0.f, 0.f};

  // prologue: W(0), W(1), X(c0=0) in flight
  issueW(0);
  issueW(1);
  issueX(0, 0);

  for (int c0i = 0; c0i < 4; ++c0i) {
    if (c0i == 0) asm volatile("s_waitcnt vmcnt(0)" ::: "memory");
    else          asm volatile("s_waitcnt vmcnt(4)" ::: "memory");  // X + W(c0i,0) retired
    __builtin_amdgcn_s_barrier();        // raw: no auto-drain; X dbuf rendezvous
    const int buf = c0i & 1;

#pragma unroll
    for (int tap = 0; tap < 9; ++tap) {
      if (tap) asm volatile("s_waitcnt vmcnt(4)" ::: "memory");  // W(tap) resident
      const int pb = (c0i + tap) & 1;    // = (c0i*9+tap)&1, 9 odd
      const int tapoff = (tap / 3) * 58 + (tap - (tap / 3) * 3) - 59;
      const uint16_t* wl = &Wb[wave][pb][0];

      int xaddr[8], xsw[8];
#pragma unroll
      for (int n = 0; n < 8; ++n) {
        int r = offn[n] + tapoff;
        xaddr[n] = r << 6;
        xsw[n] = r & 7;
      }
      short8 af[2][2], bf[2][8];
#pragma unroll
      for (int m = 0; m < 2; ++m)
#pragma unroll
        for (int kk = 0; kk < 2; ++kk)
          af[m][kk] = *(const short8*)&wl[((m * 2 + kk) * 64 + lane) * 8];
#pragma unroll
      for (int kk = 0; kk < 2; ++kk)
#pragma unroll
        for (int n = 0; n < 8; ++n)
          bf[kk][n] = *(const short8*)&Xs[buf][xaddr[n] + ((((kk * 4 + chp)) ^ xsw[n]) << 3)];

      // reads retired before overwriting Wb[pb] / issuing more vmem
      asm volatile("s_waitcnt lgkmcnt(0)" ::: "memory");
      int gn = c0i * 9 + tap + 2;
      if (gn >= 36) gn -= 36;            // tail wrap: harmless warm prefetch
      issueW(gn);                        // -> Wb[pb] (same parity), reads done
      if (tap == 7 && c0i < 3) issueX(buf ^ 1, (c0i + 1) * 64);

      __builtin_amdgcn_s_setprio(1);
#pragma unroll
      for (int kk = 0; kk < 2; ++kk)
#pragma unroll
        for (int m = 0; m < 2; ++m)
#pragma unroll
          for (int n = 0; n < 8; ++n)
            acc[m][n] = __builtin_amdgcn_mfma_f32_16x16x32_bf16(af[m][kk], bf[kk][n], acc[m][n], 0, 0, 0);
      __builtin_amdgcn_s_setprio(0);
    }
  }
  asm volatile("s_waitcnt vmcnt(0)" ::: "memory");  // drain wrap prefetch before exit

  // epilogue: out = clip(acc*S + T), layout [b][co][s]
#pragma unroll
  for (int m = 0; m < 2; ++m) {
    const int cor0 = wave * 32 + m * 16 + chp * 4;
    float Sv[4], Tv[4];
#pragma unroll
    for (int r = 0; r < 4; ++r) { Sv[r] = Sc[cor0 + r]; Tv[r] = Tc[cor0 + r]; }
#pragma unroll
    for (int n = 0; n < 8; ++n) {
      const int s = s0 + n * 16 + l15;
      if (s < SPAT) {
        float* op = out + ((size_t)b * COUT + cor0) * SPAT + s;
#pragma unroll
        for (int r = 0; r < 4; ++r) {
          float v = acc[m][n][r] * Sv[r] + Tv[r];
          v = fminf(1.0f, fmaxf(-1.0f, v));
          op[(size_t)r * SPAT] = v;
        }
      }
    }
  }
}

extern "C" void kernel_launch(void* const* d_in, const int* in_sizes, int n_in,
                              void* d_out, int out_size, void* d_ws, size_t ws_size,
                              hipStream_t stream) {
  const float* x     = (const float*)d_in[0];
  const float* wgt   = (const float*)d_in[1];
  const float* gamma = (const float*)d_in[2];
  const float* beta  = (const float*)d_in[3];
  const float* rmean = (const float*)d_in[4];
  const float* rvar  = (const float*)d_in[5];
  float* out = (float*)d_out;

  uint16_t* xp = (uint16_t*)d_ws;
  const size_t xp_elems = (size_t)BATCH * SPAD * CIN;        // 55.1 MB
  uint16_t* wfrag = xp + xp_elems;
  const size_t wfrag_elems = (size_t)9 * COUT * CIN;         // 1.2 MB
  float* Sc = (float*)(wfrag + wfrag_elems);
  float* Tc = Sc + COUT;

  halo_kernel<<<BATCH, 256, 0, stream>>>(xp);
  pack_x_kernel<<<dim3(49, BATCH), 256, 0, stream>>>(x, xp);
  prep_w_kernel<<<COUT, 256, 0, stream>>>(wgt, gamma, beta, rmean, rvar, wfrag, Sc, Tc);
  conv_kernel<<<dim3(25, BATCH), 512, 0, stream>>>(xp, wfrag, Sc, Tc, out);
}

// Round 5
// 359.081 us; speedup vs baseline: 1.5202x; 1.5202x over previous
//
#include <hip/hip_runtime.h>
#include <hip/hip_bf16.h>
#include <cstdint>
#include <cstddef>

// IR-Net binary conv 3x3 s1 p1 + BN(inference) + hardtanh, B=32 Cin=Cout=256 H=W=56.
// sign(x), sign(std(W)) ternary -> exact bf16 MFMA implicit GEMM.
// R5: R2 base (128co x 128px, 4 waves, acc[4][4]) + K-step 32, LDS 48KB (3 blocks/CU),
//     ONE raw s_barrier + lgkmcnt(0) per step (dbuf Ws/Xs), W reg-prefetch 2 ahead,
//     X global_load_lds pieces issued after W in vmcnt FIFO (no vmcnt(0) drains),
//     W pre-baked in swizzled LDS-image order (linear staging copy).

typedef short short8 __attribute__((ext_vector_type(8)));
typedef float floatx4 __attribute__((ext_vector_type(4)));

#define CIN   256
#define COUT  256
#define SPAT  3136   // 56*56
#define SPAD  3364   // 58*58 padded spatial
#define BATCH 32

// ---------------- weight prep: standardize, sign, scatter to swizzled LDS image ----------------
__device__ inline float block_reduce(float v, float* red, int t) {
  red[t] = v; __syncthreads();
#pragma unroll
  for (int o = 128; o > 0; o >>= 1) {
    if (t < o) red[t] += red[t + o];
    __syncthreads();
  }
  float r = red[0];
  __syncthreads();
  return r;
}

__global__ __launch_bounds__(256) void prep_w_kernel(
    const float* __restrict__ wgt, const float* __restrict__ gamma,
    const float* __restrict__ beta, const float* __restrict__ rmean,
    const float* __restrict__ rvar, uint16_t* __restrict__ wfrag,
    float* __restrict__ Sc, float* __restrict__ Tc) {
  const int co = blockIdx.x;
  const int t  = threadIdx.x;
  __shared__ float red[256];
  const float* wc = wgt + (size_t)co * 2304;
  float v[9];
#pragma unroll
  for (int j = 0; j < 9; ++j) v[j] = wc[t + j * 256];
  float s = 0.f;
#pragma unroll
  for (int j = 0; j < 9; ++j) s += v[j];
  const float total = block_reduce(s, red, t);
  const float mean = total * (1.0f / 2304.0f);
  float ss = 0.f, sa = 0.f;
#pragma unroll
  for (int j = 0; j < 9; ++j) {
    float d = v[j] - mean;
    ss += d * d;
    sa += fabsf(d);
  }
  const float var_sum = block_reduce(ss, red, t);
  const float abs_sum = block_reduce(sa, red, t);
  const float stdv = sqrtf(var_sum / 2303.0f);       // unbiased (ddof=1)
  const float mean_abs = abs_sum / (2304.0f * stdv); // mean |bw|
  const float sw = exp2f(rintf(log2f(mean_abs)));    // half-even like jnp.round

  const int z = co >> 7, row = co & 127;
#pragma unroll
  for (int j = 0; j < 9; ++j) {
    int i = t + j * 256;          // i = cin*9 + tap  (OIHW flat)
    int cin = i / 9;
    int tap = i - cin * 9;
    float d = v[j] - mean;
    uint16_t bits = (d > 0.f) ? 0x3F80u : ((d < 0.f) ? 0xBF80u : 0u); // bf16 +-1 / 0
    // LDS-image order: [z][step=c0i*9+tap][row(128)][cs(4)][e(8)], cs = c ^ ((row>>1)&3)
    int c0i = cin >> 5, cl = cin & 31;
    int c = cl >> 3, e = cl & 7;
    int cs = c ^ ((row >> 1) & 3);
    size_t flat = ((size_t)(z * 72 + c0i * 9 + tap)) * 4096 + row * 32 + cs * 8 + e;
    wfrag[flat] = bits;
  }
  if (t == 0) {
    float inv = gamma[co] / sqrtf(rvar[co] + 1e-5f);
    Sc[co] = sw * inv;
    Tc[co] = beta[co] - rmean[co] * inv;
  }
}

// ---------------- halo clear: zero only the 228 pad pixels per image ----------------
__global__ __launch_bounds__(256) void halo_kernel(uint16_t* __restrict__ xp) {
  const int b = blockIdx.x;
  uint16_t* xpb = xp + (size_t)b * SPAD * CIN;
  const short8 z = (short8){0, 0, 0, 0, 0, 0, 0, 0};
  for (int q = threadIdx.x; q < 228 * 32; q += 256) {
    int p = q >> 5, c = q & 31;
    int pp;
    if (p < 58)       pp = p;                      // top row 0
    else if (p < 116) pp = 57 * 58 + (p - 58);     // bottom row 57
    else if (p < 172) pp = (p - 116 + 1) * 58;     // left col, rows 1..56
    else              pp = (p - 172 + 1) * 58 + 57;// right col, rows 1..56
    *(short8*)(xpb + (size_t)pp * CIN + c * 8) = z;
  }
}

// ---------------- activation pack: sign(x) -> bf16, padded [b][58*58][cin] ----------------
__global__ __launch_bounds__(256) void pack_x_kernel(const float* __restrict__ x,
                                                     uint16_t* __restrict__ xp) {
  const int b   = blockIdx.y;
  const int s0  = blockIdx.x * 64;
  const int tid = threadIdx.x;
  __shared__ uint16_t xt[64][272];
  const int g  = tid >> 6;
  const int si = tid & 63;
  const float* xb = x + ((size_t)b * CIN + g * 64) * SPAT + s0 + si;
#pragma unroll 4
  for (int c2 = 0; c2 < 32; ++c2) {
    float v0 = xb[(size_t)(2 * c2) * SPAT];
    float v1 = xb[(size_t)(2 * c2 + 1) * SPAT];
    uint32_t b0 = (v0 > 0.f) ? 0x3F80u : ((v0 < 0.f) ? 0xBF80u : 0u);
    uint32_t b1 = (v1 > 0.f) ? 0x3F80u : ((v1 < 0.f) ? 0xBF80u : 0u);
    *(uint32_t*)&xt[si][g * 64 + 2 * c2] = b0 | (b1 << 16);
  }
  __syncthreads();
  const int row = tid >> 2;
  const int sub = tid & 3;
  const int s = s0 + row;
  const int h = s / 56, w = s - h * 56;
  uint16_t* dst = xp + ((size_t)b * SPAD + (size_t)(h + 1) * 58 + (w + 1)) * CIN + sub * 64;
#pragma unroll
  for (int j = 0; j < 8; ++j)
    *(short8*)(dst + j * 8) = *(const short8*)&xt[row][sub * 64 + j * 8];
}

// ---------------- async global->LDS, 16B ----------------
__device__ __forceinline__ void gload_lds16(const void* g, void* l) {
  __builtin_amdgcn_global_load_lds(
      (const __attribute__((address_space(1))) uint32_t*)g,
      (__attribute__((address_space(3))) uint32_t*)l, 16, 0, 0);
}

// ---------------- binary conv as implicit GEMM (bf16 MFMA) ----------------
// Block: 128co x 128px, one image; 4 waves, wave = 64co x 64px, acc[4][4].
// 72 steps (8 c0i x 9 taps), K=32 per step. One raw barrier per step.
__global__ __launch_bounds__(256, 3) void conv_kernel(
    const uint16_t* __restrict__ xp, const uint16_t* __restrict__ wfrag,
    const float* __restrict__ Sc, const float* __restrict__ Tc,
    float* __restrict__ out) {
  const int tile = blockIdx.x;           // 0..24
  const int b    = blockIdx.y;           // 0..31
  const int co0  = blockIdx.z * 128;
  const int s0   = tile * 128;

  const int tid  = threadIdx.x;
  const int lane = tid & 63;
  const int wave = tid >> 6;
  const int wco  = (wave >> 1) * 64;     // wave tile: 64co x 64px
  const int wp   = (wave & 1) * 64;
  const int l15  = lane & 15;
  const int chp  = lane >> 4;            // k-chunk 0..3 (8 cin each)

  __shared__ uint16_t Xs[2][256 * 32];   // 2 x 16KB, span rows x 32cin, swizzled
  __shared__ uint16_t Ws[2][128 * 32];   // 2 x 8KB, swizzled image

  const int h0   = s0 / 56;
  const int base = s0 + 2 * h0;          // padded(s)=s+2h+59; base = padded(s0)-59

  int offn[4];
#pragma unroll
  for (int n = 0; n < 4; ++n) {
    int s = s0 + wp + n * 16 + l15;
    int sc = s < SPAT ? s : SPAT - 1;    // dummy px clamped (stores masked)
    int h = sc / 56;
    offn[n] = sc + 2 * h + 59 - base;    // in [0, 249]
  }
  int aoff[4];
#pragma unroll
  for (int m = 0; m < 4; ++m) {
    int r = wco + m * 16 + l15;
    aoff[m] = r * 32 + ((chp ^ ((r >> 1) & 3)) << 3);
  }

  const uint16_t* xb  = xp + (size_t)b * SPAD * CIN;
  const uint16_t* wfp = wfrag + (size_t)(blockIdx.z * 72) * 4096;

  // X piece j (0..3) for cin-block c0e, into Xs[bufx]; 1 chunk/thread
  auto issueXpiece = [&](int bufx, int c0e, int j) {
    int q = j * 256 + tid;               // 1024 x 16B chunks
    int row = q >> 2, c = q & 3;
    int gr = base + row;
    if (gr > SPAD - 1) gr = SPAD - 1;    // clamp: only feeds dummy px
    gload_lds16(xb + (size_t)gr * CIN + c0e + ((c ^ ((row >> 1) & 3)) << 3),
                &Xs[bufx][q << 3]);
  };

  short8 wr0, wr1;                        // W(step+1) staging regs
  auto loadW = [&](int g) {               // g = step index 0..71
    const uint16_t* src = wfp + (size_t)g * 4096 + tid * 16;
    wr0 = *(const short8*)src;
    wr1 = *(const short8*)(src + 8);
  };
  auto writeW = [&](int p1) {
    uint16_t* d = &Ws[p1][tid * 16];
    *(short8*)d = wr0;
    *(short8*)(d + 8) = wr1;
  };

  floatx4 acc[4][4];
#pragma unroll
  for (int m = 0; m < 4; ++m)
#pragma unroll
    for (int n = 0; n < 4; ++n) acc[m][n] = (floatx4){0.f, 0.f, 0.f, 0.f};

  // prologue: W(0) -> regs -> Ws[0]; X(c0i=0) in flight; W(1) -> regs
  loadW(0);
#pragma unroll
  for (int j = 0; j < 4; ++j) issueXpiece(0, 0, j);
  writeW(0);                              // compiler waits W(0) loads only
  loadW(1);
  asm volatile("s_waitcnt vmcnt(2)" ::: "memory");  // X resident; W(1) may fly
  asm volatile("s_waitcnt lgkmcnt(0)" ::: "memory");
  __builtin_amdgcn_s_barrier();

#pragma unroll 1
  for (int c0i = 0; c0i < 8; ++c0i) {
    const int buf = c0i & 1;
    const int c0n = (c0i + 1) << 5;
#pragma unroll
    for (int tap = 0; tap < 9; ++tap) {
      const int step = c0i * 9 + tap;
      const int p    = (c0i + tap) & 1;   // = step & 1
      const int tapoff = (tap / 3) * 58 + (tap - (tap / 3) * 3) - 59;

      // LDS -> regs (current step)
      short8 af[4], bf[4];
#pragma unroll
      for (int m = 0; m < 4; ++m)
        af[m] = *(const short8*)&Ws[p][aoff[m]];
#pragma unroll
      for (int n = 0; n < 4; ++n) {
        int rn = offn[n] + tapoff;
        bf[n] = *(const short8*)&Xs[buf][rn * 32 + ((chp ^ ((rn >> 1) & 3)) << 3)];
      }

      // stage next: W(step+1) regs -> Ws[p^1]; issue W(step+2); X pieces taps 0..3
      writeW(p ^ 1);
      {
        int gn = step + 2;
        if (gn > 71) gn = 71;             // tail: harmless refetch
        loadW(gn);
      }
      if (tap < 4 && c0i < 7) issueXpiece(buf ^ 1, c0n, tap);

      __builtin_amdgcn_s_setprio(1);
#pragma unroll
      for (int m = 0; m < 4; ++m)
#pragma unroll
        for (int n = 0; n < 4; ++n)
          acc[m][n] = __builtin_amdgcn_mfma_f32_16x16x32_bf16(af[m], bf[n], acc[m][n], 0, 0, 0);
      __builtin_amdgcn_s_setprio(0);

      asm volatile("s_waitcnt lgkmcnt(0)" ::: "memory");  // my reads+writes done
      __builtin_amdgcn_s_barrier();                       // raw: vmem stays in flight
    }
  }
  asm volatile("s_waitcnt vmcnt(0)" ::: "memory");  // drain tail W prefetch

  // epilogue: out = clip(acc*S + T), layout [b][co][s]
#pragma unroll
  for (int m = 0; m < 4; ++m) {
    const int cor0 = co0 + wco + m * 16 + chp * 4;
    float Sv[4], Tv[4];
#pragma unroll
    for (int r = 0; r < 4; ++r) { Sv[r] = Sc[cor0 + r]; Tv[r] = Tc[cor0 + r]; }
#pragma unroll
    for (int n = 0; n < 4; ++n) {
      const int s = s0 + wp + n * 16 + l15;
      if (s < SPAT) {
        float* op = out + ((size_t)b * COUT + cor0) * SPAT + s;
#pragma unroll
        for (int r = 0; r < 4; ++r) {
          float v = acc[m][n][r] * Sv[r] + Tv[r];
          v = fminf(1.0f, fmaxf(-1.0f, v));
          op[(size_t)r * SPAT] = v;
        }
      }
    }
  }
}

extern "C" void kernel_launch(void* const* d_in, const int* in_sizes, int n_in,
                              void* d_out, int out_size, void* d_ws, size_t ws_size,
                              hipStream_t stream) {
  const float* x     = (const float*)d_in[0];
  const float* wgt   = (const float*)d_in[1];
  const float* gamma = (const float*)d_in[2];
  const float* beta  = (const float*)d_in[3];
  const float* rmean = (const float*)d_in[4];
  const float* rvar  = (const float*)d_in[5];
  float* out = (float*)d_out;

  uint16_t* xp = (uint16_t*)d_ws;
  const size_t xp_elems = (size_t)BATCH * SPAD * CIN;        // 55.1 MB
  uint16_t* wfrag = xp + xp_elems;
  const size_t wfrag_elems = (size_t)2 * 72 * 4096;          // 1.2 MB
  float* Sc = (float*)(wfrag + wfrag_elems);
  float* Tc = Sc + COUT;

  halo_kernel<<<BATCH, 256, 0, stream>>>(xp);
  pack_x_kernel<<<dim3(49, BATCH), 256, 0, stream>>>(x, xp);
  prep_w_kernel<<<COUT, 256, 0, stream>>>(wgt, gamma, beta, rmean, rvar, wfrag, Sc, Tc);
  conv_kernel<<<dim3(25, BATCH, 2), 256, 0, stream>>>(xp, wfrag, Sc, Tc, out);
}

// Round 6
// 135.116 us; speedup vs baseline: 4.0399x; 2.6576x over previous
//
#include <hip/hip_runtime.h>
#include <hip/hip_bf16.h>
#include <cstdint>
#include <cstddef>

// IR-Net binary conv 3x3 s1 p1 + BN(inference) + hardtanh, B=32 Cin=Cout=256 H=W=56.
// Ternary operands -> EXACT int8 MFMA implicit GEMM (mfma_i32_16x16x64_i8, 2x bf16 rate).
// R6: R2's proven schedule (syncthreads pairs, reg-staged W 2-ahead) with i8:
//     18 steps (2 cin-blocks x 9 taps), K-step 128 cin = full 128B lines,
//     Xs single span buffer (32KB, 8-slot XOR swizzle), Ws dbuf 2x16KB, 64KB LDS.

typedef int int4v __attribute__((ext_vector_type(4)));

#define CIN   256
#define COUT  256
#define SPAT  3136   // 56*56
#define SPAD  3364   // 58*58 padded spatial
#define BATCH 32

// ---------------- weight prep: standardize, sign, scatter to swizzled i8 LDS image ----------------
__device__ inline float block_reduce(float v, float* red, int t) {
  red[t] = v; __syncthreads();
#pragma unroll
  for (int o = 128; o > 0; o >>= 1) {
    if (t < o) red[t] += red[t + o];
    __syncthreads();
  }
  float r = red[0];
  __syncthreads();
  return r;
}

__global__ __launch_bounds__(256) void prep_w_kernel(
    const float* __restrict__ wgt, const float* __restrict__ gamma,
    const float* __restrict__ beta, const float* __restrict__ rmean,
    const float* __restrict__ rvar, int8_t* __restrict__ wfrag,
    float* __restrict__ Sc, float* __restrict__ Tc) {
  const int co = blockIdx.x;
  const int t  = threadIdx.x;
  __shared__ float red[256];
  const float* wc = wgt + (size_t)co * 2304;
  float v[9];
#pragma unroll
  for (int j = 0; j < 9; ++j) v[j] = wc[t + j * 256];
  float s = 0.f;
#pragma unroll
  for (int j = 0; j < 9; ++j) s += v[j];
  const float total = block_reduce(s, red, t);
  const float mean = total * (1.0f / 2304.0f);
  float ss = 0.f, sa = 0.f;
#pragma unroll
  for (int j = 0; j < 9; ++j) {
    float d = v[j] - mean;
    ss += d * d;
    sa += fabsf(d);
  }
  const float var_sum = block_reduce(ss, red, t);
  const float abs_sum = block_reduce(sa, red, t);
  const float stdv = sqrtf(var_sum / 2303.0f);       // unbiased (ddof=1)
  const float mean_abs = abs_sum / (2304.0f * stdv); // mean |bw|
  const float sw = exp2f(rintf(log2f(mean_abs)));    // half-even like jnp.round

  const int z = co >> 7, row = co & 127;
#pragma unroll
  for (int j = 0; j < 9; ++j) {
    int i = t + j * 256;          // i = cin*9 + tap  (OIHW flat)
    int cin = i / 9;
    int tap = i - cin * 9;
    float d = v[j] - mean;
    int8_t bits = (d > 0.f) ? (int8_t)1 : ((d < 0.f) ? (int8_t)-1 : (int8_t)0);
    // swizzled LDS-image order: [z][step][row(128)][cs(8)*16 + e], cs = chunk ^ (row&7)
    int c0i = cin >> 7, cl = cin & 127;
    int chunk = cl >> 4, e = cl & 15;
    int step = c0i * 9 + tap;
    size_t flat = ((size_t)((z * 18 + step) * 128 + row)) * 128
                + ((chunk ^ (row & 7)) << 4) + e;
    wfrag[flat] = bits;
  }
  if (t == 0) {
    float inv = gamma[co] / sqrtf(rvar[co] + 1e-5f);
    Sc[co] = sw * inv;
    Tc[co] = beta[co] - rmean[co] * inv;
  }
}

// ---------------- halo clear: zero the 228 pad pixels per image (i8) ----------------
__global__ __launch_bounds__(256) void halo_kernel(int8_t* __restrict__ xp) {
  const int b = blockIdx.x;
  int8_t* xpb = xp + (size_t)b * SPAD * CIN;
  const int4v z = (int4v){0, 0, 0, 0};
  for (int q = threadIdx.x; q < 228 * 16; q += 256) {
    int p = q >> 4, c = q & 15;
    int pp;
    if (p < 58)       pp = p;                      // top row 0
    else if (p < 116) pp = 57 * 58 + (p - 58);     // bottom row 57
    else if (p < 172) pp = (p - 116 + 1) * 58;     // left col, rows 1..56
    else              pp = (p - 172 + 1) * 58 + 57;// right col, rows 1..56
    *(int4v*)(xpb + (size_t)pp * CIN + c * 16) = z;
  }
}

// ---------------- activation pack: sign(x) -> i8, padded [b][58*58][cin] ----------------
__global__ __launch_bounds__(256) void pack_x_kernel(const float* __restrict__ x,
                                                     int8_t* __restrict__ xp) {
  const int b   = blockIdx.y;
  const int s0  = blockIdx.x * 64;
  const int tid = threadIdx.x;
  __shared__ uint8_t xt[64][272];        // 64 px x 256 cin bytes (+16 pad)
  const int g  = tid >> 6;               // cin quarter 0..3
  const int si = tid & 63;               // px within chunk
#pragma unroll
  for (int k = 0; k < 4; ++k) {          // 16 cin per iter -> one 16B LDS store
    const int cin16 = (g * 4 + k) * 16;
    const float* src = x + ((size_t)b * CIN + cin16) * SPAT + s0 + si;
    uint32_t w[4] = {0u, 0u, 0u, 0u};
#pragma unroll
    for (int e = 0; e < 16; ++e) {
      float v = src[(size_t)e * SPAT];
      uint32_t sb = (v > 0.f) ? 1u : ((v < 0.f) ? 0xFFu : 0u);
      w[e >> 2] |= sb << ((e & 3) * 8);
    }
    *(int4v*)&xt[si][cin16] = (int4v){(int)w[0], (int)w[1], (int)w[2], (int)w[3]};
  }
  __syncthreads();
  const int row = tid >> 2;              // px 0..63
  const int sub = tid & 3;               // 64-cin quarter
  const int s = s0 + row;
  const int h = s / 56;
  int8_t* dst = xp + ((size_t)b * SPAD + (size_t)(s + 2 * h + 59)) * CIN + sub * 64;
#pragma unroll
  for (int j = 0; j < 4; ++j)
    *(int4v*)(dst + j * 16) = *(const int4v*)&xt[row][sub * 64 + j * 16];
}

// ---------------- async global->LDS, 16B ----------------
__device__ __forceinline__ void gload_lds16(const void* g, void* l) {
  __builtin_amdgcn_global_load_lds(
      (const __attribute__((address_space(1))) uint32_t*)g,
      (__attribute__((address_space(3))) uint32_t*)l, 16, 0, 0);
}

// ---------------- binary conv as implicit GEMM (i8 MFMA) ----------------
// Block: 128co x 128px, one image; 4 waves, wave = 64co x 64px, acc[4][4] i32.
// 18 steps (2 c0i x 9 taps), K=128 cin per step (2 mfma K-batches of 64).
__global__ __launch_bounds__(256, 2) void conv_kernel(
    const int8_t* __restrict__ xp, const int8_t* __restrict__ wfrag,
    const float* __restrict__ Sc, const float* __restrict__ Tc,
    float* __restrict__ out) {
  const int tile = blockIdx.x;           // 0..24
  const int b    = blockIdx.y;           // 0..31
  const int z    = blockIdx.z;           // co half
  const int co0  = z * 128;
  const int s0   = tile * 128;

  const int tid  = threadIdx.x;
  const int lane = tid & 63;
  const int wave = tid >> 6;
  const int wco  = (wave >> 1) * 64;     // wave tile: 64co x 64px
  const int wp   = (wave & 1) * 64;
  const int l15  = lane & 15;
  const int chp  = lane >> 4;            // 16B k-chunk position 0..3

  __shared__ uint8_t Xs[256 * 128];      // 32 KB: span rows x 128 cin, swizzled
  __shared__ uint8_t Ws[2][16384];       // 2 x 16 KB: swizzled W image, dbuf

  const int h0   = s0 / 56;
  const int base = s0 + 2 * h0;          // padded(s)=s+2h+59; base = padded(s0)-59

  int offn[4];
#pragma unroll
  for (int n = 0; n < 4; ++n) {
    int s = s0 + wp + n * 16 + l15;
    int sc = s < SPAT ? s : SPAT - 1;    // dummy px clamped (stores masked)
    int h = sc / 56;
    offn[n] = sc + 2 * h + 59 - base;    // in [0, 249]
  }

  const int8_t* xb  = xp + (size_t)b * SPAD * CIN;
  const int8_t* wfp = wfrag + (size_t)z * 18 * 16384;

  auto issueX = [&](int c0e) {           // 8 x 16B chunks per thread, one c0 half
#pragma unroll
    for (int j = 0; j < 8; ++j) {
      int q = j * 256 + tid;             // 2048 x 16B chunks
      int row = q >> 3, c = q & 7;
      int gr = base + row;
      if (gr > SPAD - 1) gr = SPAD - 1;  // clamp: only feeds dummy px
      gload_lds16(xb + (size_t)gr * CIN + c0e + ((c ^ (row & 7)) << 4),
                  &Xs[(size_t)q << 4]);
    }
  };

  int4v wreg[4];
  auto loadW = [&](int g) {              // linear copy of pre-swizzled image
    const int8_t* src = wfp + (size_t)g * 16384 + tid * 16;
#pragma unroll
    for (int j = 0; j < 4; ++j) wreg[j] = *(const int4v*)(src + j * 4096);
  };
  auto writeW = [&](int p1) {            // lane-contiguous b128 stores
    uint8_t* d = Ws[p1] + tid * 16;
#pragma unroll
    for (int j = 0; j < 4; ++j) *(int4v*)(d + j * 4096) = wreg[j];
  };

  int4v acc[4][4];
#pragma unroll
  for (int m = 0; m < 4; ++m)
#pragma unroll
    for (int n = 0; n < 4; ++n) acc[m][n] = (int4v){0, 0, 0, 0};

  // prologue: W(0)->regs; X(c0=0) in flight; W(0)->Ws[0]; W(1)->regs
  loadW(0);
  issueX(0);
  writeW(0);                             // waits only the W(0) loads
  loadW(1);
  __syncthreads();                       // drains all: Xs + Ws[0] + wreg ready

#pragma unroll 1
  for (int step = 0; step < 18; ++step) {
    const int p   = step & 1;
    const int tap = step < 9 ? step : step - 9;
    const int tapoff = (tap / 3) * 58 + (tap - (tap / 3) * 3) - 59;
    int xrow[4];
#pragma unroll
    for (int n = 0; n < 4; ++n) xrow[n] = offn[n] + tapoff;

    __builtin_amdgcn_s_setprio(1);
#pragma unroll
    for (int kb = 0; kb < 2; ++kb) {
      const int cb = kb * 4 + chp;
      int4v af[4], bf[4];
#pragma unroll
      for (int m = 0; m < 4; ++m) {
        int r = wco + m * 16 + l15;
        af[m] = *(const int4v*)&Ws[p][r * 128 + ((cb ^ (r & 7)) << 4)];
      }
#pragma unroll
      for (int n = 0; n < 4; ++n) {
        int r = xrow[n];
        bf[n] = *(const int4v*)&Xs[r * 128 + ((cb ^ (r & 7)) << 4)];
      }
#pragma unroll
      for (int m = 0; m < 4; ++m)
#pragma unroll
        for (int n = 0; n < 4; ++n)
          acc[m][n] = __builtin_amdgcn_mfma_i32_16x16x64_i8(af[m], bf[n], acc[m][n], 0, 0, 0);
    }
    __builtin_amdgcn_s_setprio(0);

    __syncthreads();                     // all readers of Ws/Xs done
    if (step < 17) {
      writeW(p ^ 1);                     // wreg = W(step+1) -> other buffer
      if (step + 2 < 18) loadW(step + 2);
    }
    if (step == 8) issueX(128);          // restage Xs with cin 128..255
    __syncthreads();                     // stage visible (drains vm+lgkm)
  }

  // epilogue: out = clip((float)acc * S + T), layout [b][co][s]
#pragma unroll
  for (int m = 0; m < 4; ++m) {
    const int cor0 = co0 + wco + m * 16 + chp * 4;
    float Sv[4], Tv[4];
#pragma unroll
    for (int r = 0; r < 4; ++r) { Sv[r] = Sc[cor0 + r]; Tv[r] = Tc[cor0 + r]; }
#pragma unroll
    for (int n = 0; n < 4; ++n) {
      const int s = s0 + wp + n * 16 + l15;
      if (s < SPAT) {
        float* op = out + ((size_t)b * COUT + cor0) * SPAT + s;
#pragma unroll
        for (int r = 0; r < 4; ++r) {
          float v = (float)acc[m][n][r] * Sv[r] + Tv[r];
          v = fminf(1.0f, fmaxf(-1.0f, v));
          op[(size_t)r * SPAT] = v;
        }
      }
    }
  }
}

extern "C" void kernel_launch(void* const* d_in, const int* in_sizes, int n_in,
                              void* d_out, int out_size, void* d_ws, size_t ws_size,
                              hipStream_t stream) {
  const float* x     = (const float*)d_in[0];
  const float* wgt   = (const float*)d_in[1];
  const float* gamma = (const float*)d_in[2];
  const float* beta  = (const float*)d_in[3];
  const float* rmean = (const float*)d_in[4];
  const float* rvar  = (const float*)d_in[5];
  float* out = (float*)d_out;

  int8_t* xp = (int8_t*)d_ws;
  const size_t xp_bytes = (size_t)BATCH * SPAD * CIN;        // 27.6 MB
  int8_t* wfrag = xp + xp_bytes;
  const size_t wfrag_bytes = (size_t)2 * 18 * 16384;         // 590 KB
  float* Sc = (float*)(wfrag + wfrag_bytes);
  float* Tc = Sc + COUT;

  halo_kernel<<<BATCH, 256, 0, stream>>>(xp);
  pack_x_kernel<<<dim3(49, BATCH), 256, 0, stream>>>(x, xp);
  prep_w_kernel<<<COUT, 256, 0, stream>>>(wgt, gamma, beta, rmean, rvar, wfrag, Sc, Tc);
  conv_kernel<<<dim3(25, BATCH, 2), 256, 0, stream>>>(xp, wfrag, Sc, Tc, out);
}

// Round 7
// 116.981 us; speedup vs baseline: 4.6662x; 1.1550x over previous
//
#include <hip/hip_runtime.h>
#include <hip/hip_bf16.h>
#include <cstdint>
#include <cstddef>

// IR-Net binary conv 3x3 s1 p1 + BN(inference) + hardtanh, B=32 Cin=Cout=256 H=W=56.
// Ternary operands -> EXACT int8 MFMA implicit GEMM (mfma_i32_16x16x64_i8).
// R7 = R6 dataflow with fixed synchronization: ONE raw s_barrier + lgkmcnt(0)
//     per step (19 barriers vs 36 draining syncthreads), W global prefetch never
//     barrier-drained (counted vmcnt at next-step writeW, overlaps MFMA),
//     X restage drain paid once per block (step 8).

typedef int int4v __attribute__((ext_vector_type(4)));

#define CIN   256
#define COUT  256
#define SPAT  3136   // 56*56
#define SPAD  3364   // 58*58 padded spatial
#define BATCH 32

// ---------------- weight prep: standardize, sign, scatter to swizzled i8 LDS image ----------------
__device__ inline float block_reduce(float v, float* red, int t) {
  red[t] = v; __syncthreads();
#pragma unroll
  for (int o = 128; o > 0; o >>= 1) {
    if (t < o) red[t] += red[t + o];
    __syncthreads();
  }
  float r = red[0];
  __syncthreads();
  return r;
}

__global__ __launch_bounds__(256) void prep_w_kernel(
    const float* __restrict__ wgt, const float* __restrict__ gamma,
    const float* __restrict__ beta, const float* __restrict__ rmean,
    const float* __restrict__ rvar, int8_t* __restrict__ wfrag,
    float* __restrict__ Sc, float* __restrict__ Tc) {
  const int co = blockIdx.x;
  const int t  = threadIdx.x;
  __shared__ float red[256];
  const float* wc = wgt + (size_t)co * 2304;
  float v[9];
#pragma unroll
  for (int j = 0; j < 9; ++j) v[j] = wc[t + j * 256];
  float s = 0.f;
#pragma unroll
  for (int j = 0; j < 9; ++j) s += v[j];
  const float total = block_reduce(s, red, t);
  const float mean = total * (1.0f / 2304.0f);
  float ss = 0.f, sa = 0.f;
#pragma unroll
  for (int j = 0; j < 9; ++j) {
    float d = v[j] - mean;
    ss += d * d;
    sa += fabsf(d);
  }
  const float var_sum = block_reduce(ss, red, t);
  const float abs_sum = block_reduce(sa, red, t);
  const float stdv = sqrtf(var_sum / 2303.0f);       // unbiased (ddof=1)
  const float mean_abs = abs_sum / (2304.0f * stdv); // mean |bw|
  const float sw = exp2f(rintf(log2f(mean_abs)));    // half-even like jnp.round

  const int z = co >> 7, row = co & 127;
#pragma unroll
  for (int j = 0; j < 9; ++j) {
    int i = t + j * 256;          // i = cin*9 + tap  (OIHW flat)
    int cin = i / 9;
    int tap = i - cin * 9;
    float d = v[j] - mean;
    int8_t bits = (d > 0.f) ? (int8_t)1 : ((d < 0.f) ? (int8_t)-1 : (int8_t)0);
    // swizzled LDS-image order: [z][step][row(128)][cs(8)*16 + e], cs = chunk ^ (row&7)
    int c0i = cin >> 7, cl = cin & 127;
    int chunk = cl >> 4, e = cl & 15;
    int step = c0i * 9 + tap;
    size_t flat = ((size_t)((z * 18 + step) * 128 + row)) * 128
                + ((chunk ^ (row & 7)) << 4) + e;
    wfrag[flat] = bits;
  }
  if (t == 0) {
    float inv = gamma[co] / sqrtf(rvar[co] + 1e-5f);
    Sc[co] = sw * inv;
    Tc[co] = beta[co] - rmean[co] * inv;
  }
}

// ---------------- halo clear: zero the 228 pad pixels per image (i8) ----------------
__global__ __launch_bounds__(256) void halo_kernel(int8_t* __restrict__ xp) {
  const int b = blockIdx.x;
  int8_t* xpb = xp + (size_t)b * SPAD * CIN;
  const int4v z = (int4v){0, 0, 0, 0};
  for (int q = threadIdx.x; q < 228 * 16; q += 256) {
    int p = q >> 4, c = q & 15;
    int pp;
    if (p < 58)       pp = p;                      // top row 0
    else if (p < 116) pp = 57 * 58 + (p - 58);     // bottom row 57
    else if (p < 172) pp = (p - 116 + 1) * 58;     // left col, rows 1..56
    else              pp = (p - 172 + 1) * 58 + 57;// right col, rows 1..56
    *(int4v*)(xpb + (size_t)pp * CIN + c * 16) = z;
  }
}

// ---------------- activation pack: sign(x) -> i8, padded [b][58*58][cin] ----------------
__global__ __launch_bounds__(256) void pack_x_kernel(const float* __restrict__ x,
                                                     int8_t* __restrict__ xp) {
  const int b   = blockIdx.y;
  const int s0  = blockIdx.x * 64;
  const int tid = threadIdx.x;
  __shared__ uint8_t xt[64][272];        // 64 px x 256 cin bytes (+16 pad)
  const int g  = tid >> 6;               // cin quarter 0..3
  const int si = tid & 63;               // px within chunk
#pragma unroll
  for (int k = 0; k < 4; ++k) {          // 16 cin per iter -> one 16B LDS store
    const int cin16 = (g * 4 + k) * 16;
    const float* src = x + ((size_t)b * CIN + cin16) * SPAT + s0 + si;
    uint32_t w[4] = {0u, 0u, 0u, 0u};
#pragma unroll
    for (int e = 0; e < 16; ++e) {
      float v = src[(size_t)e * SPAT];
      uint32_t sb = (v > 0.f) ? 1u : ((v < 0.f) ? 0xFFu : 0u);
      w[e >> 2] |= sb << ((e & 3) * 8);
    }
    *(int4v*)&xt[si][cin16] = (int4v){(int)w[0], (int)w[1], (int)w[2], (int)w[3]};
  }
  __syncthreads();
  const int row = tid >> 2;              // px 0..63
  const int sub = tid & 3;               // 64-cin quarter
  const int s = s0 + row;
  const int h = s / 56;
  int8_t* dst = xp + ((size_t)b * SPAD + (size_t)(s + 2 * h + 59)) * CIN + sub * 64;
#pragma unroll
  for (int j = 0; j < 4; ++j)
    *(int4v*)(dst + j * 16) = *(const int4v*)&xt[row][sub * 64 + j * 16];
}

// ---------------- async global->LDS, 16B ----------------
__device__ __forceinline__ void gload_lds16(const void* g, void* l) {
  __builtin_amdgcn_global_load_lds(
      (const __attribute__((address_space(1))) uint32_t*)g,
      (__attribute__((address_space(3))) uint32_t*)l, 16, 0, 0);
}

// ---------------- binary conv as implicit GEMM (i8 MFMA) ----------------
// Block: 128co x 128px, one image; 4 waves, wave = 64co x 64px, acc[4][4] i32.
// 18 steps (2 c0i x 9 taps), K=128 cin per step. ONE raw barrier per step.
__global__ __launch_bounds__(256, 2) void conv_kernel(
    const int8_t* __restrict__ xp, const int8_t* __restrict__ wfrag,
    const float* __restrict__ Sc, const float* __restrict__ Tc,
    float* __restrict__ out) {
  const int tile = blockIdx.x;           // 0..24
  const int b    = blockIdx.y;           // 0..31
  const int z    = blockIdx.z;           // co half
  const int co0  = z * 128;
  const int s0   = tile * 128;

  const int tid  = threadIdx.x;
  const int lane = tid & 63;
  const int wave = tid >> 6;
  const int wco  = (wave >> 1) * 64;     // wave tile: 64co x 64px
  const int wp   = (wave & 1) * 64;
  const int l15  = lane & 15;
  const int chp  = lane >> 4;            // 16B k-chunk position 0..3

  __shared__ uint8_t Xs[256 * 128];      // 32 KB: span rows x 128 cin, swizzled
  __shared__ uint8_t Ws[2][16384];       // 2 x 16 KB: swizzled W image, dbuf

  const int h0   = s0 / 56;
  const int base = s0 + 2 * h0;          // padded(s)=s+2h+59; base = padded(s0)-59

  int offn[4];
#pragma unroll
  for (int n = 0; n < 4; ++n) {
    int s = s0 + wp + n * 16 + l15;
    int sc = s < SPAT ? s : SPAT - 1;    // dummy px clamped (stores masked)
    int h = sc / 56;
    offn[n] = sc + 2 * h + 59 - base;    // in [59, 192]
  }

  const int8_t* xb  = xp + (size_t)b * SPAD * CIN;
  const int8_t* wfp = wfrag + (size_t)z * 18 * 16384;

  auto issueX = [&](int c0e) {           // 8 x 16B chunks per thread, one c0 half
#pragma unroll
    for (int j = 0; j < 8; ++j) {
      int q = j * 256 + tid;             // 2048 x 16B chunks
      int row = q >> 3, c = q & 7;
      int gr = base + row;
      if (gr > SPAD - 1) gr = SPAD - 1;  // clamp: only feeds dummy px
      gload_lds16(xb + (size_t)gr * CIN + c0e + ((c ^ (row & 7)) << 4),
                  &Xs[(size_t)q << 4]);
    }
  };

  int4v wreg[4];
  auto loadW = [&](int g) {              // linear copy of pre-swizzled image
    const int8_t* src = wfp + (size_t)g * 16384 + tid * 16;
#pragma unroll
    for (int j = 0; j < 4; ++j) wreg[j] = *(const int4v*)(src + j * 4096);
  };
  auto writeW = [&](int p1) {            // lane-contiguous b128 stores
    uint8_t* d = Ws[p1] + tid * 16;
#pragma unroll
    for (int j = 0; j < 4; ++j) *(int4v*)(d + j * 4096) = wreg[j];
  };

  int4v acc[4][4];
#pragma unroll
  for (int m = 0; m < 4; ++m)
#pragma unroll
    for (int n = 0; n < 4; ++n) acc[m][n] = (int4v){0, 0, 0, 0};

  // prologue: W(0)->regs; X(c0=0) in flight; W(0)->Ws[0]; W(1)->regs
  loadW(0);
  issueX(0);
  writeW(0);                             // compiler waits the W(0) loads only
  loadW(1);
  asm volatile("s_waitcnt vmcnt(0) lgkmcnt(0)" ::: "memory");  // X + Ws[0] ready
  __builtin_amdgcn_s_barrier();

#pragma unroll 1
  for (int step = 0; step < 18; ++step) {
    const int p   = step & 1;
    const int tap = step < 9 ? step : step - 9;
    const int tapoff = (tap / 3) * 58 + (tap - (tap / 3) * 3) - 59;

    // ---- LDS -> regs (current step)
    short8_dummy:;
    int4v af[4], bf[4][2];               // bf per kb to keep reads up front
#pragma unroll
    for (int kb = 0; kb < 2; ++kb) {
      const int cb = kb * 4 + chp;
#pragma unroll
      for (int n = 0; n < 4; ++n) {
        int r = offn[n] + tapoff;
        bf[n][kb] = *(const int4v*)&Xs[r * 128 + ((cb ^ (r & 7)) << 4)];
      }
    }

    // ---- stage next step (W) while MFMA runs
    if (step < 17) writeW(p ^ 1);        // wreg = W(step+1); counted vmcnt here
    if (step < 16) loadW(step + 2);      // global, stays in flight across barrier

    __builtin_amdgcn_s_setprio(1);
#pragma unroll
    for (int kb = 0; kb < 2; ++kb) {
      const int cb = kb * 4 + chp;
#pragma unroll
      for (int m = 0; m < 4; ++m) {
        int r = wco + m * 16 + l15;
        af[m] = *(const int4v*)&Ws[p][r * 128 + ((cb ^ (r & 7)) << 4)];
      }
#pragma unroll
      for (int m = 0; m < 4; ++m)
#pragma unroll
        for (int n = 0; n < 4; ++n)
          acc[m][n] = __builtin_amdgcn_mfma_i32_16x16x64_i8(af[m], bf[n][kb], acc[m][n], 0, 0, 0);
    }
    __builtin_amdgcn_s_setprio(0);

    asm volatile("s_waitcnt lgkmcnt(0)" ::: "memory");  // my ds reads+writes retired
    __builtin_amdgcn_s_barrier();                       // raw: vmem stays in flight

    if (step == 8) {                     // all waves' cin0-127 reads are done
      issueX(128);                       // overwrite Xs with cin 128..255
      asm volatile("s_waitcnt vmcnt(0)" ::: "memory");  // own DMA retired (once/block)
      __builtin_amdgcn_s_barrier();                     // everyone's DMA retired
    }
  }

  // epilogue: out = clip((float)acc * S + T), layout [b][co][s]
#pragma unroll
  for (int m = 0; m < 4; ++m) {
    const int cor0 = co0 + wco + m * 16 + chp * 4;
    float Sv[4], Tv[4];
#pragma unroll
    for (int r = 0; r < 4; ++r) { Sv[r] = Sc[cor0 + r]; Tv[r] = Tc[cor0 + r]; }
#pragma unroll
    for (int n = 0; n < 4; ++n) {
      const int s = s0 + wp + n * 16 + l15;
      if (s < SPAT) {
        float* op = out + ((size_t)b * COUT + cor0) * SPAT + s;
#pragma unroll
        for (int r = 0; r < 4; ++r) {
          float v = (float)acc[m][n][r] * Sv[r] + Tv[r];
          v = fminf(1.0f, fmaxf(-1.0f, v));
          op[(size_t)r * SPAT] = v;
        }
      }
    }
  }
}

extern "C" void kernel_launch(void* const* d_in, const int* in_sizes, int n_in,
                              void* d_out, int out_size, void* d_ws, size_t ws_size,
                              hipStream_t stream) {
  const float* x     = (const float*)d_in[0];
  const float* wgt   = (const float*)d_in[1];
  const float* gamma = (const float*)d_in[2];
  const float* beta  = (const float*)d_in[3];
  const float* rmean = (const float*)d_in[4];
  const float* rvar  = (const float*)d_in[5];
  float* out = (float*)d_out;

  int8_t* xp = (int8_t*)d_ws;
  const size_t xp_bytes = (size_t)BATCH * SPAD * CIN;        // 27.6 MB
  int8_t* wfrag = xp + xp_bytes;
  const size_t wfrag_bytes = (size_t)2 * 18 * 16384;         // 590 KB
  float* Sc = (float*)(wfrag + wfrag_bytes);
  float* Tc = Sc + COUT;

  halo_kernel<<<BATCH, 256, 0, stream>>>(xp);
  pack_x_kernel<<<dim3(49, BATCH), 256, 0, stream>>>(x, xp);
  prep_w_kernel<<<COUT, 256, 0, stream>>>(wgt, gamma, beta, rmean, rvar, wfrag, Sc, Tc);
  conv_kernel<<<dim3(25, BATCH, 2), 256, 0, stream>>>(xp, wfrag, Sc, Tc, out);
}

// Round 8
// 102.262 us; speedup vs baseline: 5.3378x; 1.1439x over previous
//
#include <hip/hip_runtime.h>
#include <hip/hip_bf16.h>
#include <cstdint>
#include <cstddef>

// IR-Net binary conv 3x3 s1 p1 + BN(inference) + hardtanh, B=32 Cin=Cout=256 H=W=56.
// Ternary operands -> EXACT int8 MFMA implicit GEMM (mfma_i32_16x16x64_i8).
// R8: barrier-free main loop. W fragments load global->regs (1-step prefetch,
//     L2-resident 590KB buffer); X both cin-halves staged to LDS in prologue
//     (dbuf, 144B padded rows -> affine addrs, full 18-step unroll => all LDS
//     reads are base+imm with zero per-step VALU). One vmcnt(8)+barrier at the
//     half boundary; no other loop barriers.

typedef int int4v __attribute__((ext_vector_type(4)));

#define CIN   256
#define COUT  256
#define SPAT  3136   // 56*56
#define SPAD  3364   // 58*58 padded spatial
#define BATCH 32
#define XROWB 144    // 128 data bytes + 16 pad (bank stride 36 -> ~2-way, free)
#define XBUFB (256 * XROWB)   // 36864 B per cin-half

// ---------------- weight prep: standardize, sign, scatter to A-fragment order ----------------
__device__ inline float block_reduce(float v, float* red, int t) {
  red[t] = v; __syncthreads();
#pragma unroll
  for (int o = 128; o > 0; o >>= 1) {
    if (t < o) red[t] += red[t + o];
    __syncthreads();
  }
  float r = red[0];
  __syncthreads();
  return r;
}

__global__ __launch_bounds__(256) void prep_w_kernel(
    const float* __restrict__ wgt, const float* __restrict__ gamma,
    const float* __restrict__ beta, const float* __restrict__ rmean,
    const float* __restrict__ rvar, int8_t* __restrict__ wfrag,
    float* __restrict__ Sc, float* __restrict__ Tc) {
  const int co = blockIdx.x;
  const int t  = threadIdx.x;
  __shared__ float red[256];
  const float* wc = wgt + (size_t)co * 2304;
  float v[9];
#pragma unroll
  for (int j = 0; j < 9; ++j) v[j] = wc[t + j * 256];
  float s = 0.f;
#pragma unroll
  for (int j = 0; j < 9; ++j) s += v[j];
  const float total = block_reduce(s, red, t);
  const float mean = total * (1.0f / 2304.0f);
  float ss = 0.f, sa = 0.f;
#pragma unroll
  for (int j = 0; j < 9; ++j) {
    float d = v[j] - mean;
    ss += d * d;
    sa += fabsf(d);
  }
  const float var_sum = block_reduce(ss, red, t);
  const float abs_sum = block_reduce(sa, red, t);
  const float stdv = sqrtf(var_sum / 2303.0f);       // unbiased (ddof=1)
  const float mean_abs = abs_sum / (2304.0f * stdv); // mean |bw|
  const float sw = exp2f(rintf(log2f(mean_abs)));    // half-even like jnp.round

  const int z = co >> 7, row = co & 127;
  const int wv = row >> 6, m = (row >> 4) & 3, l15w = row & 15;
#pragma unroll
  for (int j = 0; j < 9; ++j) {
    int i = t + j * 256;          // i = cin*9 + tap  (OIHW flat)
    int cin = i / 9;
    int tap = i - cin * 9;
    float d = v[j] - mean;
    int8_t bits = (d > 0.f) ? (int8_t)1 : ((d < 0.f) ? (int8_t)-1 : (int8_t)0);
    // A-fragment order: [z][g=c0i*9+tap][wv][m*2+kb][lane(64)][e(16)]
    int c0i = cin >> 7, cl = cin & 127;
    int chunk = cl >> 4;                 // 0..7 (16 cin each)
    int kb = chunk >> 2, chp = chunk & 3, e = cl & 15;
    int lane = chp * 16 + l15w;
    int g = c0i * 9 + tap;
    size_t flat = (size_t)z * 294912 + (size_t)(g * 2 + wv) * 8192
                + (m * 2 + kb) * 1024 + lane * 16 + e;
    wfrag[flat] = bits;
  }
  if (t == 0) {
    float inv = gamma[co] / sqrtf(rvar[co] + 1e-5f);
    Sc[co] = sw * inv;
    Tc[co] = beta[co] - rmean[co] * inv;
  }
}

// ---------------- halo clear: zero the 228 pad pixels per image (i8) ----------------
__global__ __launch_bounds__(256) void halo_kernel(int8_t* __restrict__ xp) {
  const int b = blockIdx.x;
  int8_t* xpb = xp + (size_t)b * SPAD * CIN;
  const int4v z = (int4v){0, 0, 0, 0};
  for (int q = threadIdx.x; q < 228 * 16; q += 256) {
    int p = q >> 4, c = q & 15;
    int pp;
    if (p < 58)       pp = p;                      // top row 0
    else if (p < 116) pp = 57 * 58 + (p - 58);     // bottom row 57
    else if (p < 172) pp = (p - 116 + 1) * 58;     // left col, rows 1..56
    else              pp = (p - 172 + 1) * 58 + 57;// right col, rows 1..56
    *(int4v*)(xpb + (size_t)pp * CIN + c * 16) = z;
  }
}

// ---------------- activation pack: sign(x) -> i8, padded [b][58*58][cin] ----------------
__global__ __launch_bounds__(256) void pack_x_kernel(const float* __restrict__ x,
                                                     int8_t* __restrict__ xp) {
  const int b   = blockIdx.y;
  const int s0  = blockIdx.x * 64;
  const int tid = threadIdx.x;
  __shared__ uint8_t xt[64][272];        // 64 px x 256 cin bytes (+16 pad)
  const int g  = tid >> 6;               // cin quarter 0..3
  const int si = tid & 63;               // px within chunk
#pragma unroll
  for (int k = 0; k < 4; ++k) {          // 16 cin per iter -> one 16B LDS store
    const int cin16 = (g * 4 + k) * 16;
    const float* src = x + ((size_t)b * CIN + cin16) * SPAT + s0 + si;
    uint32_t w[4] = {0u, 0u, 0u, 0u};
#pragma unroll
    for (int e = 0; e < 16; ++e) {
      float v = src[(size_t)e * SPAT];
      uint32_t sb = (v > 0.f) ? 1u : ((v < 0.f) ? 0xFFu : 0u);
      w[e >> 2] |= sb << ((e & 3) * 8);
    }
    *(int4v*)&xt[si][cin16] = (int4v){(int)w[0], (int)w[1], (int)w[2], (int)w[3]};
  }
  __syncthreads();
  const int row = tid >> 2;              // px 0..63
  const int sub = tid & 3;               // 64-cin quarter
  const int s = s0 + row;
  const int h = s / 56;
  int8_t* dst = xp + ((size_t)b * SPAD + (size_t)(s + 2 * h + 59)) * CIN + sub * 64;
#pragma unroll
  for (int j = 0; j < 4; ++j)
    *(int4v*)(dst + j * 16) = *(const int4v*)&xt[row][sub * 64 + j * 16];
}

// ---------------- async global->LDS, 16B ----------------
__device__ __forceinline__ void gload_lds16(const void* g, void* l) {
  __builtin_amdgcn_global_load_lds(
      (const __attribute__((address_space(1))) uint32_t*)g,
      (__attribute__((address_space(3))) uint32_t*)l, 16, 0, 0);
}

// ---------------- binary conv as implicit GEMM (i8 MFMA) ----------------
// Block: 128co x 128px, one image; 4 waves, wave = 64co x 64px, acc[4][4] i32.
// 18 steps (2 cin-halves x 9 taps), fully unrolled, barrier-free except the
// half-boundary rendezvous. W: global->reg prefetch. X: both halves in LDS.
__global__ __launch_bounds__(256, 2) void conv_kernel(
    const int8_t* __restrict__ xp, const int8_t* __restrict__ wfrag,
    const float* __restrict__ Sc, const float* __restrict__ Tc,
    float* __restrict__ out) {
  const int tile = blockIdx.x;           // 0..24
  const int b    = blockIdx.y;           // 0..31
  const int z    = blockIdx.z;           // co half
  const int co0  = z * 128;
  const int s0   = tile * 128;

  const int tid  = threadIdx.x;
  const int lane = tid & 63;
  const int wave = tid >> 6;
  const int wv   = wave >> 1;            // co 64-half within block
  const int wco  = wv * 64;
  const int wp   = (wave & 1) * 64;      // px 64-half
  const int l15  = lane & 15;
  const int chp  = lane >> 4;            // 16B k-chunk position 0..3

  __shared__ uint8_t XsF[2 * XBUFB];     // 72 KB: two cin-halves, 144B rows

  const int h0   = s0 / 56;
  const int base = s0 + 2 * h0;          // padded(s)=s+2h+59; base = padded(s0)-59

  // per-lane Xs base pointers (chp baked in); row r = offn+tapoff in [0,249]
  const uint8_t* xn[4];
#pragma unroll
  for (int n = 0; n < 4; ++n) {
    int s = s0 + wp + n * 16 + l15;
    int sc = s < SPAT ? s : SPAT - 1;    // dummy px clamped (stores masked)
    int h = sc / 56;
    int offn = sc + 2 * h + 59 - base;   // in [59, 190]
    xn[n] = XsF + (offn - 59) * XROWB + chp * 16;
  }

  const int8_t* xb  = xp + (size_t)b * SPAD * CIN;
  const int8_t* wba = wfrag + (size_t)z * 294912 + (size_t)wv * 8192 + lane * 16;

  // stage one cin-half: 2304 16B chunks (256 rows x 9), 9 per thread
  auto issueX = [&](int bufi, int c0e) {
#pragma unroll
    for (int j = 0; j < 9; ++j) {
      int q   = j * 256 + tid;
      int row = (q * 7282) >> 16;        // q/9 exact for q<2304
      int sub = q - row * 9;
      int gr  = base + row;
      if (gr > SPAD - 1) gr = SPAD - 1;  // clamp: only feeds dummy px / pad
      int gsub = (sub == 8) ? 0 : sub;   // pad chunk: load anything in-bounds
      gload_lds16(xb + (size_t)gr * CIN + c0e + gsub * 16,
                  XsF + bufi * XBUFB + q * 16);
    }
  };

  int4v af[2][8];                        // [step parity][m*2+kb], reg dbuf
  auto loadAf = [&](int g, int pb) {
#pragma unroll
    for (int q8 = 0; q8 < 8; ++q8)
      af[pb][q8] = *(const int4v*)(wba + (size_t)g * 16384 + q8 * 1024);
  };

  int4v acc[4][4];
#pragma unroll
  for (int m = 0; m < 4; ++m)
#pragma unroll
    for (int n = 0; n < 4; ++n) acc[m][n] = (int4v){0, 0, 0, 0};

  // prologue: X half0 -> LDS; af(0) -> regs; X half1 -> LDS (stays in flight)
  issueX(0, 0);                          // 9 vmem
  loadAf(0, 0);                          // 8 vmem
  issueX(1, 128);                        // 9 vmem
  asm volatile("s_waitcnt vmcnt(17)" ::: "memory");  // half0 resident
  __builtin_amdgcn_s_barrier();
  asm volatile("" ::: "memory");

#pragma unroll
  for (int s = 0; s < 18; ++s) {
    const int pb  = s & 1;
    const int tap = s < 9 ? s : s - 9;
    const int tapoff = (tap / 3) * 58 + (tap - (tap / 3) * 3) - 59;
    const int IMM = (tapoff + 59) * XROWB + (s >= 9 ? XBUFB : 0);

    if (s == 9) {                        // half1 rendezvous: af(9) stays in flight
      asm volatile("s_waitcnt vmcnt(8)" ::: "memory");
      __builtin_amdgcn_s_barrier();
      asm volatile("" ::: "memory");
    }

    // bf reads: base + compile-time offset, zero addr VALU
    int4v bf[8];
#pragma unroll
    for (int kb = 0; kb < 2; ++kb)
#pragma unroll
      for (int n = 0; n < 4; ++n)
        bf[kb * 4 + n] = *(const int4v*)(xn[n] + IMM + kb * 64);

    if (s < 17) loadAf(s + 1, pb ^ 1);   // W prefetch, counted-vmcnt consumed next step

    __builtin_amdgcn_s_setprio(1);
#pragma unroll
    for (int kb = 0; kb < 2; ++kb)
#pragma unroll
      for (int m = 0; m < 4; ++m)
#pragma unroll
        for (int n = 0; n < 4; ++n)
          acc[m][n] = __builtin_amdgcn_mfma_i32_16x16x64_i8(
              af[pb][m * 2 + kb], bf[kb * 4 + n], acc[m][n], 0, 0, 0);
    __builtin_amdgcn_s_setprio(0);
  }

  // epilogue: out = clip((float)acc * S + T), layout [b][co][s]
#pragma unroll
  for (int m = 0; m < 4; ++m) {
    const int cor0 = co0 + wco + m * 16 + chp * 4;
    float Sv[4], Tv[4];
#pragma unroll
    for (int r = 0; r < 4; ++r) { Sv[r] = Sc[cor0 + r]; Tv[r] = Tc[cor0 + r]; }
#pragma unroll
    for (int n = 0; n < 4; ++n) {
      const int s = s0 + wp + n * 16 + l15;
      if (s < SPAT) {
        float* op = out + ((size_t)b * COUT + cor0) * SPAT + s;
#pragma unroll
        for (int r = 0; r < 4; ++r) {
          float v = (float)acc[m][n][r] * Sv[r] + Tv[r];
          v = fminf(1.0f, fmaxf(-1.0f, v));
          op[(size_t)r * SPAT] = v;
        }
      }
    }
  }
}

extern "C" void kernel_launch(void* const* d_in, const int* in_sizes, int n_in,
                              void* d_out, int out_size, void* d_ws, size_t ws_size,
                              hipStream_t stream) {
  const float* x     = (const float*)d_in[0];
  const float* wgt   = (const float*)d_in[1];
  const float* gamma = (const float*)d_in[2];
  const float* beta  = (const float*)d_in[3];
  const float* rmean = (const float*)d_in[4];
  const float* rvar  = (const float*)d_in[5];
  float* out = (float*)d_out;

  int8_t* xp = (int8_t*)d_ws;
  const size_t xp_bytes = (size_t)BATCH * SPAD * CIN;        // 27.6 MB
  int8_t* wfrag = xp + xp_bytes;
  const size_t wfrag_bytes = (size_t)2 * 294912;             // 590 KB
  float* Sc = (float*)(wfrag + wfrag_bytes);
  float* Tc = Sc + COUT;

  halo_kernel<<<BATCH, 256, 0, stream>>>(xp);
  pack_x_kernel<<<dim3(49, BATCH), 256, 0, stream>>>(x, xp);
  prep_w_kernel<<<COUT, 256, 0, stream>>>(wgt, gamma, beta, rmean, rvar, wfrag, Sc, Tc);
  conv_kernel<<<dim3(25, BATCH, 2), 256, 0, stream>>>(xp, wfrag, Sc, Tc, out);
}